// Round 8
// baseline (1622.502 us; speedup 1.0000x reference)
//
#include <hip/hip_runtime.h>
#include <hip/hip_bf16.h>
#include <hip/hip_fp16.h>

// GroupAttention: B=4, N=8192, C=1024, H=16, Dh=64, g=4, G=2048.
//
// Round-6 measured: 1195us, absmax 0.0156. GEMM1 = 831 TF = the 2-phase
// structural ceiling (MfmaUtil 36.5%). This round: GEMM1 -> 256x256 8-phase
// schedule (T2 swizzle + T3/T4 counted vmcnt + T5 setprio). QKV stays f32 so
// numerics are identical to round-6 (isolates the new-GEMM experiment).
//
// Pipeline per slice (Ms=4096 rows):
//   presplit: x_s -> XA = [Ah|Al] (Ms x 2048 fp16)
//   gemm8:    QKV(f32) = XA @ Bq   (8-phase 256^2, 3 K-passes via plane offsets)
//   attn:     4x4 softmax per (b,g,h) f32; writes O as [Oh|Ol] over XA
//   gemm3:    out(f32) = O @ w_proj + b_proj (proven 2-phase 128^2)
// ws (80 MiB @ Ms=4096): XA 16M | QKV 48M | Bq 12M | Bp 4M   (tiers: 32M/20M)

typedef float    f32x4 __attribute__((ext_vector_type(4)));
typedef _Float16 f16x8 __attribute__((ext_vector_type(8)));
typedef _Float16 f16x4 __attribute__((ext_vector_type(4)));

__device__ __forceinline__ void gload16(const _Float16* g, _Float16* l) {
  __builtin_amdgcn_global_load_lds((const __attribute__((address_space(1))) void*)g,
                                   (__attribute__((address_space(3))) void*)l,
                                   16, 0, 0);
}

#define FULL_BAR() do { asm volatile("" ::: "memory"); \
  __builtin_amdgcn_s_barrier(); asm volatile("" ::: "memory"); } while (0)

// ---------------- x slice (Ms x 1024 f32) -> XA = [Ah | Al] (Ms x 2048 fp16) ----
__global__ void presplit_kernel(const float* __restrict__ x, _Float16* __restrict__ XA) {
  int gid = blockIdx.x * 256 + threadIdx.x;
  int row = gid >> 8, c4 = gid & 255;
  f32x4 v = *reinterpret_cast<const f32x4*>(x + ((size_t)gid << 2));
  f16x4 hi, lo;
#pragma unroll
  for (int c = 0; c < 4; ++c) {
    _Float16 h = (_Float16)v[c];
    hi[c] = h; lo[c] = (_Float16)(v[c] - (float)h);
  }
  size_t o = (size_t)row * 2048 + (c4 << 2);
  *reinterpret_cast<f16x4*>(XA + o)        = hi;
  *reinterpret_cast<f16x4*>(XA + o + 1024) = lo;
}

// ---------------- W (1024 x N row-major) -> BT = [Bh | Bl] (N x 2048, k-contig) --
__global__ void wsplit_kernel(const float* __restrict__ W,
                              _Float16* __restrict__ BT, int N) {
  __shared__ float tile[64][65];
  int n0 = blockIdx.x * 64, k0 = blockIdx.y * 64;
  int t = threadIdx.x, tr = t >> 4, tc = t & 15;
#pragma unroll
  for (int it = 0; it < 4; ++it) {
    int k = k0 + tr + it * 16;
    f32x4 v = *reinterpret_cast<const f32x4*>(W + (size_t)k * N + n0 + (tc << 2));
#pragma unroll
    for (int c = 0; c < 4; ++c) tile[tr + it * 16][(tc << 2) + c] = v[c];
  }
  __syncthreads();
#pragma unroll
  for (int it = 0; it < 4; ++it) {
    int n = n0 + tr + it * 16;
    f16x4 hi, lo;
#pragma unroll
    for (int c = 0; c < 4; ++c) {
      float f = tile[(tc << 2) + c][tr + it * 16];
      _Float16 h = (_Float16)f;
      hi[c] = h; lo[c] = (_Float16)(f - (float)h);
    }
    size_t off = (size_t)n * 2048 + k0 + (tc << 2);
    *reinterpret_cast<f16x4*>(BT + off)        = hi;
    *reinterpret_cast<f16x4*>(BT + off + 1024) = lo;
  }
}

// ---------------- gemm8: 256x256 8-phase split GEMM, C = f32 (M x 3072) --------
// A: M x 2048 [Ah|Al].  B: 3072 x 2048 [Bh|Bl] (N-major).  K-tiles: 48 = 3 passes
// x 16 (pass0 AhBh, pass1 AlBh, pass2 AhBl via plane offsets).  BK=64 as two
// k-halves of 32; 4 half-tiles per K-tile, one staged per phase.  LDS: 4 rotating
// 16KiB slots per operand (128 KiB).  Swizzle: chunk ^= (chunk>>2)&3 (both sides).
__launch_bounds__(512, 1)
__global__ void gemm8_kernel(const _Float16* __restrict__ A,
                             const _Float16* __restrict__ B,
                             float* __restrict__ C, int M) {
  __shared__ _Float16 lds[65536];        // A slots: s*8192 ; B slots: 32768 + s*8192

  int nwg = gridDim.x, bid = blockIdx.x;
  // bijective XCD swizzle for any nwg (m204)
  int q = nwg >> 3, r = nwg & 7, xcd = bid & 7, loc = bid >> 3;
  int swz = (xcd < r ? xcd * (q + 1) : r * (q + 1) + (xcd - r) * q) + loc;
  int Mt = M >> 8;
  int tm = swz % Mt, tn = swz / Mt;      // M-major: neighbors share the B panel
  int brow = tm << 8, bcol = tn << 8;

  int t = threadIdx.x;
  int wid = t >> 6, lane = t & 63;
  int wm = wid >> 2, wn = wid & 3;       // 2x4 waves; per-wave output 128x64
  int lr = lane & 15, kb = lane >> 4;

  // stage one half-tile (256 rows x 32 k, 16 KiB): 2 gload16/thread.
  // phys chunk p holds logical chunk p ^ ((p>>2)&3)  (involution).
  auto stage = [&](int isB, int KT, int kh) {
    int plane = isB ? (((KT >> 4) == 2) ? 1024 : 0) : (((KT >> 4) == 1) ? 1024 : 0);
    int kbase = plane + (KT & 15) * 64 + kh * 32;
    const _Float16* src = isB ? B : A;
    int rowBase = isB ? bcol : brow;
    _Float16* slot = lds + (isB ? 32768 : 0) + (((2 * KT + kh) & 3) << 13);
#pragma unroll
    for (int qq = 0; qq < 2; ++qq) {
      int p = (qq << 9) | t;
      int row = p >> 2;
      int cc = (p & 3) ^ (row & 3);
      gload16(src + (size_t)(rowBase + row) * 2048 + kbase + (cc << 3),
              slot + (((qq << 9) | (wid << 6)) << 3));   // wave-uniform dest (m104)
    }
  };

  // fragment read: logical (R,kc) -> fp16 idx R*32 + ((kc^(R&3))<<3); R&3==lr&3
  int aSwz = (kb ^ (lr & 3)) << 3;
  int aRow = (wm * 128 + lr) * 32 + aSwz;   // + mi*512
  int bRow = (wn * 64 + lr) * 32 + aSwz;    // + ni*512

  f32x4 acc[8][4] = {};

  // prologue: KT0 all 4 halves + KT1 kh0 halves; force KT0 landed
  stage(1, 0, 0); stage(0, 0, 0); stage(1, 0, 1); stage(0, 0, 1);
  stage(1, 1, 0); stage(0, 1, 0);
  asm volatile("s_waitcnt vmcnt(4)" ::: "memory");
  FULL_BAR();

  for (int KT = 0; KT < 48; ++KT) {
    const _Float16* sA0 = lds + (((2 * KT) & 3) << 13);
    const _Float16* sA1 = lds + (((2 * KT + 1) & 3) << 13);
    const _Float16* sB0 = lds + 32768 + (((2 * KT) & 3) << 13);
    const _Float16* sB1 = lds + 32768 + (((2 * KT + 1) & 3) << 13);
    f16x8 aq[4], bq[4];

    // ---- phase 0: kh=0, frags mi 0-3 ----
#pragma unroll
    for (int i = 0; i < 4; ++i) aq[i] = *reinterpret_cast<const f16x8*>(sA0 + aRow + i * 512);
#pragma unroll
    for (int i = 0; i < 4; ++i) bq[i] = *reinterpret_cast<const f16x8*>(sB0 + bRow + i * 512);
    if (KT + 1 < 48) stage(1, KT + 1, 1);
    FULL_BAR();
    __builtin_amdgcn_s_setprio(1);
#pragma unroll
    for (int mi = 0; mi < 4; ++mi)
#pragma unroll
      for (int ni = 0; ni < 4; ++ni)
        acc[mi][ni] = __builtin_amdgcn_mfma_f32_16x16x32_f16(aq[mi], bq[ni], acc[mi][ni], 0, 0, 0);
    __builtin_amdgcn_s_setprio(0);
    FULL_BAR();

    // ---- phase 1: kh=0, frags mi 4-7 (bq reused) ----
#pragma unroll
    for (int i = 0; i < 4; ++i) aq[i] = *reinterpret_cast<const f16x8*>(sA0 + aRow + (i + 4) * 512);
    if (KT + 1 < 48) stage(0, KT + 1, 1);
    FULL_BAR();
    __builtin_amdgcn_s_setprio(1);
#pragma unroll
    for (int mi = 0; mi < 4; ++mi)
#pragma unroll
      for (int ni = 0; ni < 4; ++ni)
        acc[mi + 4][ni] = __builtin_amdgcn_mfma_f32_16x16x32_f16(aq[mi], bq[ni], acc[mi + 4][ni], 0, 0, 0);
    __builtin_amdgcn_s_setprio(0);
    FULL_BAR();

    // ---- phase 2: kh=1, frags mi 0-3 ----
#pragma unroll
    for (int i = 0; i < 4; ++i) aq[i] = *reinterpret_cast<const f16x8*>(sA1 + aRow + i * 512);
#pragma unroll
    for (int i = 0; i < 4; ++i) bq[i] = *reinterpret_cast<const f16x8*>(sB1 + bRow + i * 512);
    if (KT + 2 < 48) stage(1, KT + 2, 0);
    FULL_BAR();
    __builtin_amdgcn_s_setprio(1);
#pragma unroll
    for (int mi = 0; mi < 4; ++mi)
#pragma unroll
      for (int ni = 0; ni < 4; ++ni)
        acc[mi][ni] = __builtin_amdgcn_mfma_f32_16x16x32_f16(aq[mi], bq[ni], acc[mi][ni], 0, 0, 0);
    __builtin_amdgcn_s_setprio(0);
    FULL_BAR();

    // ---- phase 3: kh=1, frags mi 4-7 + K-tile boundary vmcnt ----
#pragma unroll
    for (int i = 0; i < 4; ++i) aq[i] = *reinterpret_cast<const f16x8*>(sA1 + aRow + (i + 4) * 512);
    if (KT + 2 < 48) stage(0, KT + 2, 0);
    FULL_BAR();
    __builtin_amdgcn_s_setprio(1);
#pragma unroll
    for (int mi = 0; mi < 4; ++mi)
#pragma unroll
      for (int ni = 0; ni < 4; ++ni)
        acc[mi + 4][ni] = __builtin_amdgcn_mfma_f32_16x16x32_f16(aq[mi], bq[ni], acc[mi + 4][ni], 0, 0, 0);
    __builtin_amdgcn_s_setprio(0);
    if (KT < 46) asm volatile("s_waitcnt vmcnt(4)" ::: "memory");  // next tile landed,
    else         asm volatile("s_waitcnt vmcnt(0)" ::: "memory");  // 2 halves in flight
    FULL_BAR();
  }

  // C/D: col = lane&15, row = (lane>>4)*4 + reg  [m89]
  int crow0 = brow + wm * 128 + (kb << 2);
  int ccol0 = bcol + wn * 64 + lr;
#pragma unroll
  for (int mi = 0; mi < 8; ++mi)
#pragma unroll
    for (int ni = 0; ni < 4; ++ni)
#pragma unroll
      for (int rr = 0; rr < 4; ++rr)
        C[(size_t)(crow0 + mi * 16 + rr) * 3072 + ccol0 + ni * 16] = acc[mi][ni][rr];
}

// ---------------- gemm3: proven 2-phase 128^2 3-pass split GEMM (GEMM2) --------
__launch_bounds__(256)
__global__ void gemm3_kernel(const _Float16* __restrict__ A,
                             const _Float16* __restrict__ B,
                             void* __restrict__ Cptr,
                             const float* __restrict__ bias, int c16,
                             int M, int N, int ldc) {
  __shared__ _Float16 lA[128 * 32];
  __shared__ _Float16 lB[128 * 32];

  int nwg = gridDim.x, bid = blockIdx.x;
  int q8 = nwg >> 3;
  int swz = (bid & 7) * q8 + (bid >> 3);
  int Mt = M >> 7;
  int tm = swz % Mt, tn = swz / Mt;
  int brow = tm << 7, bcol = tn << 7;

  int t = threadIdx.x;
  int wv = t >> 6, lane = t & 63;
  int wrow = (wv >> 1) << 6, wcol = (wv & 1) << 6;
  int lr = lane & 15, kb = lane >> 4;

  const _Float16* pa0 = A + (size_t)(brow + (t >> 2)) * 2048 + ((t & 3) << 3);
  const _Float16* pa1 = pa0 + (size_t)64 * 2048;
  const _Float16* pb0 = B + (size_t)(bcol + (t >> 2)) * 2048 + ((t & 3) << 3);
  const _Float16* pb1 = pb0 + (size_t)64 * 2048;
  _Float16* lA0 = lA + wv * 512;
  _Float16* lA1 = lA + 2048 + wv * 512;
  _Float16* lB0 = lB + wv * 512;
  _Float16* lB1 = lB + 2048 + wv * 512;

  const _Float16* ar = lA + (wrow + lr) * 32 + kb * 8;
  const _Float16* br = lB + (wcol + lr) * 32 + kb * 8;

  f32x4 acc[4][4] = {};

  for (int pass = 0; pass < 3; ++pass) {
    int aOff = (pass == 1) ? 1024 : 0;
    int bOff = (pass == 2) ? 1024 : 0;
    for (int kt = 0; kt < 1024; kt += 32) {
      gload16(pa0 + aOff + kt, lA0);
      gload16(pa1 + aOff + kt, lA1);
      gload16(pb0 + bOff + kt, lB0);
      gload16(pb1 + bOff + kt, lB1);
      __syncthreads();
      f16x8 af[4], bf[4];
#pragma unroll
      for (int i = 0; i < 4; ++i) {
        af[i] = *reinterpret_cast<const f16x8*>(ar + i * 512);
        bf[i] = *reinterpret_cast<const f16x8*>(br + i * 512);
      }
#pragma unroll
      for (int mi = 0; mi < 4; ++mi)
#pragma unroll
        for (int ni = 0; ni < 4; ++ni)
          acc[mi][ni] = __builtin_amdgcn_mfma_f32_16x16x32_f16(af[mi], bf[ni], acc[mi][ni], 0, 0, 0);
      __syncthreads();
    }
  }

  int crow0 = brow + wrow + (kb << 2);
  int ccol0 = bcol + wcol + lr;
#pragma unroll
  for (int ni = 0; ni < 4; ++ni) {
    int col = ccol0 + (ni << 4);
    float bv = (!c16 && bias) ? bias[col] : 0.0f;
#pragma unroll
    for (int mi = 0; mi < 4; ++mi) {
#pragma unroll
      for (int rr = 0; rr < 4; ++rr) {
        int row = crow0 + (mi << 4) + rr;
        if (c16)
          ((_Float16*)Cptr)[(size_t)row * ldc + col] = (_Float16)acc[mi][ni][rr];
        else
          ((float*)Cptr)[(size_t)row * ldc + col] = acc[mi][ni][rr] + bv;
      }
    }
  }
}

// ---------------- group attention: f32 QKV in, [Oh|Ol] fp16 out over XA --------
__global__ void attn_kernel(const float* __restrict__ qkv, _Float16* __restrict__ XA) {
  int u = (blockIdx.x << 2) + (threadIdx.x >> 6);
  int lane = threadIdx.x & 63;
  int j = lane >> 4, tq = lane & 15;
  int h = u & 15, grp = u >> 4;
  size_t row = (size_t)grp * 4 + j;
  size_t idx = row * 3072 + h * 64 + (tq << 2);

  f32x4 qv = *reinterpret_cast<const f32x4*>(qkv + idx);
  f32x4 kv = *reinterpret_cast<const f32x4*>(qkv + idx + 1024);
  f32x4 vv = *reinterpret_cast<const f32x4*>(qkv + idx + 2048);
  qv *= 0.125f;

  float s[4];
#pragma unroll
  for (int e = 0; e < 4; ++e) {
    f32x4 ke;
    if (e == 0) ke = kv;
    else {
#pragma unroll
      for (int c = 0; c < 4; ++c) ke[c] = __shfl_xor(kv[c], e << 4);
    }
    float p = qv[0]*ke[0] + qv[1]*ke[1] + qv[2]*ke[2] + qv[3]*ke[3];
    p += __shfl_xor(p, 1);
    p += __shfl_xor(p, 2);
    p += __shfl_xor(p, 4);
    p += __shfl_xor(p, 8);
    s[e] = p;
  }
  float mx = fmaxf(fmaxf(s[0], s[1]), fmaxf(s[2], s[3]));
  float e0 = expf(s[0]-mx), e1 = expf(s[1]-mx), e2 = expf(s[2]-mx), e3 = expf(s[3]-mx);
  float inv = 1.0f / (e0 + e1 + e2 + e3);
  float P[4] = {e0*inv, e1*inv, e2*inv, e3*inv};

  f32x4 o = {0.0f, 0.0f, 0.0f, 0.0f};
#pragma unroll
  for (int e = 0; e < 4; ++e) {
    f32x4 ve;
    if (e == 0) ve = vv;
    else {
#pragma unroll
      for (int c = 0; c < 4; ++c) ve[c] = __shfl_xor(vv[c], e << 4);
    }
    o += P[e] * ve;
  }

  f16x4 hi, lo;
#pragma unroll
  for (int c = 0; c < 4; ++c) {
    _Float16 hh = (_Float16)o[c];
    hi[c] = hh; lo[c] = (_Float16)(o[c] - (float)hh);
  }
  size_t oo = row * 2048 + h * 64 + (tq << 2);
  *reinterpret_cast<f16x4*>(XA + oo)        = hi;
  *reinterpret_cast<f16x4*>(XA + oo + 1024) = lo;
}

// ---------------- launch ----------------
extern "C" void kernel_launch(void* const* d_in, const int* in_sizes, int n_in,
                              void* d_out, int out_size, void* d_ws, size_t ws_size,
                              hipStream_t stream) {
  const float* x      = (const float*)d_in[0];
  const float* w_qkv  = (const float*)d_in[1];
  const float* w_proj = (const float*)d_in[2];
  const float* b_proj = (const float*)d_in[3];
  float* out = (float*)d_out;
  char* ws = (char*)d_ws;

  int Ms;
  if      (ws_size >= 83886080ull) Ms = 4096;   // 80 MiB (proven: ws >= 112 MiB)
  else if (ws_size >= 33554432ull) Ms = 1024;   // 32 MiB
  else                             Ms = 256;    // 20 MiB
  const int SL = 32768 / Ms;

  size_t sXA  = (size_t)Ms * 2048 * 2;
  size_t sQKV = (size_t)Ms * 3072 * 4;
  _Float16* XA  = (_Float16*)ws;
  float*    QKV = (float*)(ws + sXA);
  _Float16* Bq  = (_Float16*)(ws + sXA + sQKV);
  _Float16* Bp  = (_Float16*)(ws + sXA + sQKV + 12582912ull);

  wsplit_kernel<<<dim3(48, 16), 256, 0, stream>>>(w_qkv, Bq, 3072);
  wsplit_kernel<<<dim3(16, 16), 256, 0, stream>>>(w_proj, Bp, 1024);

  for (int s = 0; s < SL; ++s) {
    const float* xs = x + (size_t)s * Ms * 1024;
    presplit_kernel<<<Ms, 256, 0, stream>>>(xs, XA);
    gemm8_kernel<<<(Ms >> 8) * 12, 512, 0, stream>>>(XA, Bq, QKV, Ms);
    attn_kernel<<<Ms, 256, 0, stream>>>(QKV, XA);
    gemm3_kernel<<<(Ms >> 7) * 8, 256, 0, stream>>>(
        XA, Bp, out + (size_t)s * Ms * 1024, b_proj, 0, Ms, 1024, 1024);
  }
}

// Round 10
// 1238.923 us; speedup vs baseline: 1.3096x; 1.3096x over previous
//
#include <hip/hip_runtime.h>
#include <hip/hip_bf16.h>
#include <hip/hip_fp16.h>

// GroupAttention: B=4, N=8192, C=1024, H=16, Dh=64, g=4, G=2048.
//
// Round-8 post-mortem: 8-phase GEMM regressed (722 TF) from two causes the
// counters isolated: (1) grid 192 < 256 CUs at 1 block/CU (25% idle);
// (2) swizzle chunk^=(row&3) leaves 4-way bank conflicts (7.08M). Fix:
// BM=128 x BN=256 tiles -> grid 768/256 at Ms=8192 (100% util, GEMM2 shares
// the kernel), swizzle chunk^=((row>>1)&3) -> 2-way (free). QKV stays f32:
// absmax must stay exactly 0.015625 (bit-identical product order).
// (Round-9 was an acquisition timeout; this is the audited resubmission —
// vmcnt liveness ledger, swizzle bank math, C/D algebra re-verified offline.)
//
// Pipeline per slice:
//   presplit: x_s -> XA = [Ah|Al] (Ms x 2048 fp16)
//   gemm8 NT=12: QKV(f32) = XA @ Bq   (3 K-passes AhBh+AlBh+AhBl, KT=48x64)
//   attn: 4x4 softmax per (b,g,h) f32; writes O as [Oh|Ol] over XA
//   gemm8 NT=4:  out(f32) = O @ Bp + b_proj
// ws: XA Ms*2048*2 | QKV Ms*3072*4 | Bq 12M | Bp 2M
//   Ms=8192 -> 149 MiB (T0) ; 4096 -> 80 (T1, guaranteed) ; 2048 -> 48 ; 512 -> 24

typedef float    f32x4 __attribute__((ext_vector_type(4)));
typedef _Float16 f16x8 __attribute__((ext_vector_type(8)));
typedef _Float16 f16x4 __attribute__((ext_vector_type(4)));

__device__ __forceinline__ void gload16(const _Float16* g, _Float16* l) {
  __builtin_amdgcn_global_load_lds((const __attribute__((address_space(1))) void*)g,
                                   (__attribute__((address_space(3))) void*)l,
                                   16, 0, 0);
}

#define FULL_BAR() do { asm volatile("" ::: "memory"); \
  __builtin_amdgcn_s_barrier(); asm volatile("" ::: "memory"); } while (0)

// ---------------- x slice (Ms x 1024 f32) -> XA = [Ah | Al] (Ms x 2048 fp16) ----
__global__ void presplit_kernel(const float* __restrict__ x, _Float16* __restrict__ XA) {
  int gid = blockIdx.x * 256 + threadIdx.x;
  int row = gid >> 8, c4 = gid & 255;
  f32x4 v = *reinterpret_cast<const f32x4*>(x + ((size_t)gid << 2));
  f16x4 hi, lo;
#pragma unroll
  for (int c = 0; c < 4; ++c) {
    _Float16 h = (_Float16)v[c];
    hi[c] = h; lo[c] = (_Float16)(v[c] - (float)h);
  }
  size_t o = (size_t)row * 2048 + (c4 << 2);
  *reinterpret_cast<f16x4*>(XA + o)        = hi;
  *reinterpret_cast<f16x4*>(XA + o + 1024) = lo;
}

// ---------------- W (1024 x N row-major) -> BT = [Bh | Bl] (N x 2048, k-contig) --
__global__ void wsplit_kernel(const float* __restrict__ W,
                              _Float16* __restrict__ BT, int N) {
  __shared__ float tile[64][65];
  int n0 = blockIdx.x * 64, k0 = blockIdx.y * 64;
  int t = threadIdx.x, tr = t >> 4, tc = t & 15;
#pragma unroll
  for (int it = 0; it < 4; ++it) {
    int k = k0 + tr + it * 16;
    f32x4 v = *reinterpret_cast<const f32x4*>(W + (size_t)k * N + n0 + (tc << 2));
#pragma unroll
    for (int c = 0; c < 4; ++c) tile[tr + it * 16][(tc << 2) + c] = v[c];
  }
  __syncthreads();
#pragma unroll
  for (int it = 0; it < 4; ++it) {
    int n = n0 + tr + it * 16;
    f16x4 hi, lo;
#pragma unroll
    for (int c = 0; c < 4; ++c) {
      float f = tile[(tc << 2) + c][tr + it * 16];
      _Float16 h = (_Float16)f;
      hi[c] = h; lo[c] = (_Float16)(f - (float)h);
    }
    size_t off = (size_t)n * 2048 + k0 + (tc << 2);
    *reinterpret_cast<f16x4*>(BT + off)        = hi;
    *reinterpret_cast<f16x4*>(BT + off + 1024) = lo;
  }
}

// ---------------- gemm8: 128x256 pipelined split GEMM, C = f32 ------------------
// A: M x 2048 [Ah|Al]. B: (NT*256) x 2048 [Bh|Bl] N-major. 48 KT of K=64 (3 passes
// x 16: AhBh, AlBh, AhBl). KT split in two k-halves of 32; 4 rotating half-slots
// per operand (A 8KiB, B 16KiB -> 96 KiB LDS). 2 phases/KT, 16 MFMA per barrier
// pair, counted vmcnt(3) (T3/T4), setprio (T5).
// Swizzle: phys chunk = log chunk ^ ((row>>1)&3)  -> 2-way banks (free, m136).
__launch_bounds__(512, 1)
__global__ void gemm8_kernel(const _Float16* __restrict__ A,
                             const _Float16* __restrict__ B,
                             float* __restrict__ C,
                             const float* __restrict__ bias,
                             int M, int NT, int ldc) {
  __shared__ _Float16 lds[49152];   // A slots: 4x4096 @0 ; B slots: 4x8192 @16384

  int nwg = gridDim.x, bid = blockIdx.x;
  int q = nwg >> 3, r = nwg & 7, xcd = bid & 7, loc = bid >> 3;
  int swz = (xcd < r ? xcd * (q + 1) : r * (q + 1) + (xcd - r) * q) + loc;
  int tn = swz % NT, tm = swz / NT;    // N-major: consecutive swz share A panel
  int brow = tm << 7, bcol = tn << 8;

  int t = threadIdx.x;
  int wid = t >> 6, lane = t & 63;
  int wm = wid >> 2, wn = wid & 3;     // 2x4 waves; per-wave output 64x64
  int lr = lane & 15, kb = lane >> 4;

  auto stage = [&](int isB, int KT, int kh) {
    int pass = KT >> 4;
    int kk = (KT & 15) * 64 + kh * 32;
    int slot = (2 * KT + kh) & 3;
    if (isB) {
      int kbase = ((pass == 2) ? 1024 : 0) + kk;
      _Float16* dstb = lds + 16384 + slot * 8192 + wid * 512;  // wave-uniform (m104)
#pragma unroll
      for (int qq = 0; qq < 2; ++qq) {
        int p = (qq << 9) | t;
        int row = p >> 2;
        int cc = (p & 3) ^ ((row >> 1) & 3);
        gload16(B + (size_t)(bcol + row) * 2048 + kbase + (cc << 3), dstb + qq * 4096);
      }
    } else {
      int kbase = ((pass == 1) ? 1024 : 0) + kk;
      int row = t >> 2;
      int cc = (t & 3) ^ ((row >> 1) & 3);
      gload16(A + (size_t)(brow + row) * 2048 + kbase + (cc << 3),
              lds + slot * 4096 + wid * 512);
    }
  };

  // fragment reads: row = base+lr (base % 16 == 0), chunk kb -> phys kb^((lr>>1)&3)
  int swzo = (kb ^ ((lr >> 1) & 3)) << 3;
  int aOff = (wm * 64 + lr) * 32 + swzo;
  int bOff = (wn * 64 + lr) * 32 + swzo;

  f32x4 acc[4][4] = {};

  // prologue: KT0 both halves + KT1 kh0; force KT0 landed (9 loads -> keep 3)
  stage(1, 0, 0); stage(0, 0, 0);
  stage(1, 0, 1); stage(0, 0, 1);
  stage(1, 1, 0); stage(0, 1, 0);
  asm volatile("s_waitcnt vmcnt(3)" ::: "memory");
  FULL_BAR();

  for (int KT = 0; KT < 48; ++KT) {
    const _Float16* sA0 = lds + ((2 * KT) & 3) * 4096;
    const _Float16* sA1 = lds + ((2 * KT + 1) & 3) * 4096;
    const _Float16* sB0 = lds + 16384 + ((2 * KT) & 3) * 8192;
    const _Float16* sB1 = lds + 16384 + ((2 * KT + 1) & 3) * 8192;
    f16x8 aq[4], bq[4];

    // ---- phase A: kh=0 ----
#pragma unroll
    for (int i = 0; i < 4; ++i) aq[i] = *reinterpret_cast<const f16x8*>(sA0 + aOff + i * 512);
#pragma unroll
    for (int i = 0; i < 4; ++i) bq[i] = *reinterpret_cast<const f16x8*>(sB0 + bOff + i * 512);
    if (KT + 1 < 48) { stage(1, KT + 1, 1); stage(0, KT + 1, 1); }
    FULL_BAR();
    __builtin_amdgcn_s_setprio(1);
#pragma unroll
    for (int mi = 0; mi < 4; ++mi)
#pragma unroll
      for (int ni = 0; ni < 4; ++ni)
        acc[mi][ni] = __builtin_amdgcn_mfma_f32_16x16x32_f16(aq[mi], bq[ni], acc[mi][ni], 0, 0, 0);
    __builtin_amdgcn_s_setprio(0);
    FULL_BAR();

    // ---- phase B: kh=1 ----
#pragma unroll
    for (int i = 0; i < 4; ++i) aq[i] = *reinterpret_cast<const f16x8*>(sA1 + aOff + i * 512);
#pragma unroll
    for (int i = 0; i < 4; ++i) bq[i] = *reinterpret_cast<const f16x8*>(sB1 + bOff + i * 512);
    if (KT + 2 < 48) { stage(1, KT + 2, 0); stage(0, KT + 2, 0); }
    FULL_BAR();
    __builtin_amdgcn_s_setprio(1);
#pragma unroll
    for (int mi = 0; mi < 4; ++mi)
#pragma unroll
      for (int ni = 0; ni < 4; ++ni)
        acc[mi][ni] = __builtin_amdgcn_mfma_f32_16x16x32_f16(aq[mi], bq[ni], acc[mi][ni], 0, 0, 0);
    __builtin_amdgcn_s_setprio(0);
    // counted drain: forces KT+1 fully landed, leaves KT+2 kh0 (3 loads) in flight
    if (KT < 46) asm volatile("s_waitcnt vmcnt(3)" ::: "memory");
    else         asm volatile("s_waitcnt vmcnt(0)" ::: "memory");
    FULL_BAR();
  }

  // C/D: col = lane&15, row = (lane>>4)*4 + reg  [m89]
  int crow0 = brow + wm * 64 + (kb << 2);
  int ccol0 = bcol + wn * 64 + lr;
#pragma unroll
  for (int ni = 0; ni < 4; ++ni) {
    int col = ccol0 + ni * 16;
    float bv = bias ? bias[col] : 0.0f;
#pragma unroll
    for (int mi = 0; mi < 4; ++mi)
#pragma unroll
      for (int rr = 0; rr < 4; ++rr)
        C[(size_t)(crow0 + mi * 16 + rr) * ldc + col] = acc[mi][ni][rr] + bv;
  }
}

// ---------------- group attention: f32 QKV in, [Oh|Ol] fp16 out over XA --------
__global__ void attn_kernel(const float* __restrict__ qkv, _Float16* __restrict__ XA) {
  int u = (blockIdx.x << 2) + (threadIdx.x >> 6);
  int lane = threadIdx.x & 63;
  int j = lane >> 4, tq = lane & 15;
  int h = u & 15, grp = u >> 4;
  size_t row = (size_t)grp * 4 + j;
  size_t idx = row * 3072 + h * 64 + (tq << 2);

  f32x4 qv = *reinterpret_cast<const f32x4*>(qkv + idx);
  f32x4 kv = *reinterpret_cast<const f32x4*>(qkv + idx + 1024);
  f32x4 vv = *reinterpret_cast<const f32x4*>(qkv + idx + 2048);
  qv *= 0.125f;

  float s[4];
#pragma unroll
  for (int e = 0; e < 4; ++e) {
    f32x4 ke;
    if (e == 0) ke = kv;
    else {
#pragma unroll
      for (int c = 0; c < 4; ++c) ke[c] = __shfl_xor(kv[c], e << 4);
    }
    float p = qv[0]*ke[0] + qv[1]*ke[1] + qv[2]*ke[2] + qv[3]*ke[3];
    p += __shfl_xor(p, 1);
    p += __shfl_xor(p, 2);
    p += __shfl_xor(p, 4);
    p += __shfl_xor(p, 8);
    s[e] = p;
  }
  float mx = fmaxf(fmaxf(s[0], s[1]), fmaxf(s[2], s[3]));
  float e0 = expf(s[0]-mx), e1 = expf(s[1]-mx), e2 = expf(s[2]-mx), e3 = expf(s[3]-mx);
  float inv = 1.0f / (e0 + e1 + e2 + e3);
  float P[4] = {e0*inv, e1*inv, e2*inv, e3*inv};

  f32x4 o = {0.0f, 0.0f, 0.0f, 0.0f};
#pragma unroll
  for (int e = 0; e < 4; ++e) {
    f32x4 ve;
    if (e == 0) ve = vv;
    else {
#pragma unroll
      for (int c = 0; c < 4; ++c) ve[c] = __shfl_xor(vv[c], e << 4);
    }
    o += P[e] * ve;
  }

  f16x4 hi, lo;
#pragma unroll
  for (int c = 0; c < 4; ++c) {
    _Float16 hh = (_Float16)o[c];
    hi[c] = hh; lo[c] = (_Float16)(o[c] - (float)hh);
  }
  size_t oo = row * 2048 + h * 64 + (tq << 2);
  *reinterpret_cast<f16x4*>(XA + oo)        = hi;
  *reinterpret_cast<f16x4*>(XA + oo + 1024) = lo;
}

// ---------------- launch ----------------
extern "C" void kernel_launch(void* const* d_in, const int* in_sizes, int n_in,
                              void* d_out, int out_size, void* d_ws, size_t ws_size,
                              hipStream_t stream) {
  const float* x      = (const float*)d_in[0];
  const float* w_qkv  = (const float*)d_in[1];
  const float* w_proj = (const float*)d_in[2];
  const float* b_proj = (const float*)d_in[3];
  float* out = (float*)d_out;
  char* ws = (char*)d_ws;

  int Ms;
  if      (ws_size >= 150994944ull) Ms = 8192;   // 144 MiB: full-util grids 768/256
  else if (ws_size >=  83886080ull) Ms = 4096;   //  80 MiB (guaranteed: ws>=112 MiB)
  else if (ws_size >=  50331648ull) Ms = 2048;   //  48 MiB
  else                              Ms = 512;    //  24 MiB
  const int SL = 32768 / Ms;

  size_t sXA  = (size_t)Ms * 2048 * 2;
  size_t sQKV = (size_t)Ms * 3072 * 4;
  _Float16* XA  = (_Float16*)ws;
  float*    QKV = (float*)(ws + sXA);
  _Float16* Bq  = (_Float16*)(ws + sXA + sQKV);
  _Float16* Bp  = (_Float16*)(ws + sXA + sQKV + 12582912ull);

  wsplit_kernel<<<dim3(48, 16), 256, 0, stream>>>(w_qkv, Bq, 3072);
  wsplit_kernel<<<dim3(16, 16), 256, 0, stream>>>(w_proj, Bp, 1024);

  for (int s = 0; s < SL; ++s) {
    const float* xs = x + (size_t)s * Ms * 1024;
    presplit_kernel<<<Ms, 256, 0, stream>>>(xs, XA);
    gemm8_kernel<<<(Ms >> 7) * 12, 512, 0, stream>>>(XA, Bq, QKV, nullptr, Ms, 12, 3072);
    attn_kernel<<<Ms, 256, 0, stream>>>(QKV, XA);
    gemm8_kernel<<<(Ms >> 7) * 4, 512, 0, stream>>>(
        XA, Bp, out + (size_t)s * Ms * 1024, b_proj, Ms, 4, 1024);
  }
}